// Round 6
// baseline (315.538 us; speedup 1.0000x reference)
//
#include <hip/hip_runtime.h>
#include <hip/hip_bf16.h>
#include <cstdint>
#include <cstddef>

#define NUM_NODES 500000
#define DIM 128
#define BATCH 131072
#define GRID 4096                         // = BATCH/32
#define CHUNKS (NUM_NODES * 16)           // 32B chunks per plane

typedef __attribute__((ext_vector_type(8))) short short8;
typedef __attribute__((ext_vector_type(4))) short short4_t;
typedef __attribute__((ext_vector_type(4))) float f32x4;

static __device__ __forceinline__ short f2bf(float f) {
    unsigned u = __builtin_bit_cast(unsigned, f);
    u += 0x7fffu + ((u >> 16) & 1u);   // round-to-nearest-even
    return (short)(u >> 16);
}
static __device__ __forceinline__ float bf2f(short s) {
    unsigned u = ((unsigned)(unsigned short)s) << 16;
    return __builtin_bit_cast(float, u);
}

// ---------------------------------------------------------------- init ----
__global__ void k_init(unsigned char* __restrict__ mask,
                       const float* __restrict__ Wih,
                       const float* __restrict__ Whh,
                       short* __restrict__ WbIH,
                       short* __restrict__ WbHH,
                       int do_mask) {
    int i = blockIdx.x * blockDim.x + threadIdx.x;
    if (do_mask && i < NUM_NODES) mask[i] = 0;
    if (i < 3 * DIM * DIM) {
        WbIH[i] = f2bf(Wih[i]);
        WbHH[i] = f2bf(Whh[i]);
    }
}

__global__ void k_scatter(unsigned char* __restrict__ mask, const int* __restrict__ idx) {
    int i = blockIdx.x * blockDim.x + threadIdx.x;
    if (i < BATCH) mask[idx[i]] = 1;
}

// ------------------------------------------------------------ gru phase ----
// 512 thr = 8 waves, 32 batch rows. wave w owns output dims 16w..16w+15.
// LDS 25.5KB: Xb/Hb/Vb bf16 tiles; h_new staged bf16 over dead Xb region;
// epilogue recomputes h, var from intact Hb/Vb -> coalesced stores.
__device__ __forceinline__ void gru_phase(
        int gb, int t, char* smem,
        const float* __restrict__ hidden, const float* __restrict__ variance,
        const int* __restrict__ idx, const float* __restrict__ xg,
        const short* __restrict__ WbIH, const short* __restrict__ WbHH,
        const float* __restrict__ b_ih, const float* __restrict__ b_hh,
        float* __restrict__ out0, float* __restrict__ out1) {
    short (*Xb)[136] = (short(*)[136])smem;             // bf16 x tile
    short (*Hb)[136] = (short(*)[136])(smem + 8704);    // bf16 h tile
    short (*Vb)[136] = (short(*)[136])(smem + 17408);   // bf16 variance tile
    short (*Hn)[136] = (short(*)[136])smem;             // bf16 h_new, OVERLAYS Xb only

    const int rb = gb * 32;

    // ---- stage x, gathered h, gathered variance (all bf16) ----
    for (int j = t; j < 1024; j += 512) {               // 1024 float4 chunks
        int row = j >> 5, c4 = j & 31;
        int node = idx[rb + row];
        f32x4 xv = *(const f32x4*)(xg + (size_t)(rb + row) * DIM + c4 * 4);
        f32x4 hv = *(const f32x4*)(hidden + (size_t)node * DIM + c4 * 4);
        f32x4 vv = *(const f32x4*)(variance + (size_t)node * DIM + c4 * 4);
        short4_t xs, hs, vs;
        xs.x = f2bf(xv.x); xs.y = f2bf(xv.y); xs.z = f2bf(xv.z); xs.w = f2bf(xv.w);
        hs.x = f2bf(hv.x); hs.y = f2bf(hv.y); hs.z = f2bf(hv.z); hs.w = f2bf(hv.w);
        vs.x = f2bf(vv.x); vs.y = f2bf(vv.y); vs.z = f2bf(vv.z); vs.w = f2bf(vv.w);
        *(short4_t*)&Xb[row][c4 * 4] = xs;
        *(short4_t*)&Hb[row][c4 * 4] = hs;
        *(short4_t*)&Vb[row][c4 * 4] = vs;
    }
    __syncthreads();

    const int w  = t >> 6;       // wave id 0..7
    const int l  = t & 63;
    const int c  = l & 15;
    const int gq = l >> 4;

    f32x4 acc[2][3][2] = {};     // [m-tile][gate third][0=x@Wih 1=h@Whh]

    #pragma unroll
    for (int ks = 0; ks < 4; ++ks) {
        const int k0 = ks * 32 + gq * 8;
        short8 a[2][2];
        a[0][0] = *(const short8*)&Xb[c][k0];
        a[1][0] = *(const short8*)&Xb[16 + c][k0];
        a[0][1] = *(const short8*)&Hb[c][k0];
        a[1][1] = *(const short8*)&Hb[16 + c][k0];
        #pragma unroll
        for (int th = 0; th < 3; ++th) {
            const int o = w * 16 + th * 128 + c;        // gate output row of W
            const short8 bi = *(const short8*)(WbIH + (size_t)o * DIM + k0);
            const short8 bh = *(const short8*)(WbHH + (size_t)o * DIM + k0);
            #pragma unroll
            for (int mt = 0; mt < 2; ++mt) {
                acc[mt][th][0] = __builtin_amdgcn_mfma_f32_16x16x32_bf16(a[mt][0], bi, acc[mt][th][0], 0, 0, 0);
                acc[mt][th][1] = __builtin_amdgcn_mfma_f32_16x16x32_bf16(a[mt][1], bh, acc[mt][th][1], 0, 0, 0);
            }
        }
    }
    __syncthreads();   // all MFMA LDS reads of Xb done; Xb dead -> Hn overlay ok

    // ---- gate math; lane holds (m = mt*16 + gq*4 + r, d = 16w + c) ----
    const int d = w * 16 + c;
    const float bs_r = b_ih[d]       + b_hh[d];
    const float bs_z = b_ih[d + 128] + b_hh[d + 128];
    const float bi_n = b_ih[d + 256];
    const float bh_n = b_hh[d + 256];

    #pragma unroll
    for (int mt = 0; mt < 2; ++mt) {
        #pragma unroll
        for (int r = 0; r < 4; ++r) {
            const int m = mt * 16 + gq * 4 + r;
            float s_r  = acc[mt][0][0][r] + acc[mt][0][1][r] + bs_r;
            float s_z  = acc[mt][1][0][r] + acc[mt][1][1][r] + bs_z;
            float gi_n = acc[mt][2][0][r] + bi_n;
            float gh_n = acc[mt][2][1][r] + bh_n;
            float rg = 1.f / (1.f + __expf(-s_r));
            float zg = 1.f / (1.f + __expf(-s_z));
            float aa = gi_n + rg * gh_n;
            float n  = 1.f - 2.f / (__expf(2.f * aa) + 1.f);   // tanh, inf-safe
            float h  = bf2f(Hb[m][d]);
            Hn[m][d] = f2bf((1.f - zg) * n + zg * h);
        }
    }
    __syncthreads();

    // ---- epilogue: pure LDS reads, var computed here, coalesced stores ----
    for (int j = t; j < 1024; j += 512) {
        int row = j >> 5, c4 = j & 31;
        int node = idx[rb + row];                  // L1-hot re-read
        size_t off = (size_t)node * DIM + c4 * 4;
        short4_t hns = *(short4_t*)&Hn[row][c4 * 4];
        short4_t hs  = *(short4_t*)&Hb[row][c4 * 4];
        short4_t vs  = *(short4_t*)&Vb[row][c4 * 4];
        f32x4 hn, var;
        hn.x = bf2f(hns.x); hn.y = bf2f(hns.y); hn.z = bf2f(hns.z); hn.w = bf2f(hns.w);
        float dx = hn.x - bf2f(hs.x), dy = hn.y - bf2f(hs.y);
        float dz = hn.z - bf2f(hs.z), dw = hn.w - bf2f(hs.w);
        var.x = 0.9f * bf2f(vs.x) + 0.1f * dx * dx;
        var.y = 0.9f * bf2f(vs.y) + 0.1f * dy * dy;
        var.z = 0.9f * bf2f(vs.z) + 0.1f * dz * dz;
        var.w = 0.9f * bf2f(vs.w) + 0.1f * dw * dw;
        *(f32x4*)(out0 + off) = hn;
        *(f32x4*)(out1 + off) = var;
    }
}

// ----------------------------------------------------------- copy phase ----
// grid-stride over 32B chunks; nontemporal to keep L2 for W + gather rows.
__device__ __forceinline__ void copy_phase(
        int b, int t,
        const float* __restrict__ hidden, const float* __restrict__ variance,
        const unsigned char* __restrict__ mask,   // null -> copy all
        float* __restrict__ out0, float* __restrict__ out1) {
    for (int cj = b * 512 + t; cj < CHUNKS; cj += GRID * 512) {
        int row = cj >> 4;
        if (mask && mask[row]) continue;          // gru writes this row
        size_t off = (size_t)row * DIM + (cj & 15) * 8;
        f32x4 a0 = __builtin_nontemporal_load((const f32x4*)(hidden + off));
        f32x4 a1 = __builtin_nontemporal_load((const f32x4*)(hidden + off + 4));
        f32x4 b0 = __builtin_nontemporal_load((const f32x4*)(variance + off));
        f32x4 b1 = __builtin_nontemporal_load((const f32x4*)(variance + off + 4));
        __builtin_nontemporal_store(a0, (f32x4*)(out0 + off));
        __builtin_nontemporal_store(a1, (f32x4*)(out0 + off + 4));
        __builtin_nontemporal_store(b0, (f32x4*)(out1 + off));
        __builtin_nontemporal_store(b1, (f32x4*)(out1 + off + 4));
    }
}

// ------------------------------------------------------------- fused ------
// mode 0: parity-staggered fused (even: gru->copy, odd: copy->gru)
// mode 1: copy-all only (fallback)    mode 2: gru only (fallback)
__global__ void __launch_bounds__(512)
k_main(const float* __restrict__ hidden, const float* __restrict__ variance,
       const int* __restrict__ idx, const float* __restrict__ xg,
       const short* __restrict__ WbIH, const short* __restrict__ WbHH,
       const float* __restrict__ b_ih, const float* __restrict__ b_hh,
       const unsigned char* __restrict__ mask,
       float* __restrict__ out0, float* __restrict__ out1, int mode) {
    __shared__ __align__(16) char smem[26112];
    const int b = blockIdx.x;
    const int t = threadIdx.x;
    if (mode == 1) { copy_phase(b, t, hidden, variance, nullptr, out0, out1); return; }
    if (mode == 2) {
        gru_phase(b, t, smem, hidden, variance, idx, xg, WbIH, WbHH, b_ih, b_hh, out0, out1);
        return;
    }
    if ((b & 1) == 0) {
        gru_phase(b, t, smem, hidden, variance, idx, xg, WbIH, WbHH, b_ih, b_hh, out0, out1);
        copy_phase(b, t, hidden, variance, mask, out0, out1);
    } else {
        copy_phase(b, t, hidden, variance, mask, out0, out1);
        gru_phase(b, t, smem, hidden, variance, idx, xg, WbIH, WbHH, b_ih, b_hh, out0, out1);
    }
}

// -------------------------------------------------------------- launch ----
extern "C" void kernel_launch(void* const* d_in, const int* in_sizes, int n_in,
                              void* d_out, int out_size, void* d_ws, size_t ws_size,
                              hipStream_t stream) {
    const float* hidden   = (const float*)d_in[0];
    const float* variance = (const float*)d_in[1];
    const int*   idx      = (const int*)d_in[2];
    const float* x        = (const float*)d_in[3];
    const float* Wih      = (const float*)d_in[4];
    const float* Whh      = (const float*)d_in[5];
    const float* bih      = (const float*)d_in[6];
    const float* bhh      = (const float*)d_in[7];
    float* out0 = (float*)d_out;
    float* out1 = out0 + (size_t)NUM_NODES * DIM;

    const size_t maskBytes = (size_t)NUM_NODES;               // 1 byte per node
    const size_t wBytes    = (size_t)3 * DIM * DIM * 2;       // per matrix (bf16)
    const bool   have_mask = ws_size >= maskBytes + 16 + 2 * wBytes;

    unsigned char* mask = have_mask ? (unsigned char*)d_ws : nullptr;
    short* WbIH = have_mask ? (short*)((char*)d_ws + ((maskBytes + 15) & ~size_t(15)))
                            : (short*)d_ws;
    short* WbHH = WbIH + 3 * DIM * DIM;

    k_init<<<(NUM_NODES + 255) / 256, 256, 0, stream>>>(
        mask ? mask : (unsigned char*)d_ws, Wih, Whh, WbIH, WbHH, have_mask ? 1 : 0);

    if (have_mask) {
        k_scatter<<<BATCH / 256, 256, 0, stream>>>(mask, idx);
        k_main<<<GRID, 512, 0, stream>>>(hidden, variance, idx, x,
                                         WbIH, WbHH, bih, bhh, mask, out0, out1, 0);
    } else {
        // fallback: copy-all, then gru overwrites its rows (no race: separate dispatches)
        k_main<<<GRID, 512, 0, stream>>>(hidden, variance, idx, x,
                                         WbIH, WbHH, bih, bhh, nullptr, out0, out1, 1);
        k_main<<<GRID, 512, 0, stream>>>(hidden, variance, idx, x,
                                         WbIH, WbHH, bih, bhh, nullptr, out0, out1, 2);
    }
}